// Round 1
// baseline (153.268 us; speedup 1.0000x reference)
//
#include <hip/hip_runtime.h>
#include <math.h>

// Capsule dynamic routing, fully fused: one block per (b, c) pair.
// B=256, C=10, N=1152, Din=8, U=16, 3 routing iterations.
// u_hat kept entirely in registers: thread t owns u = (t&3)*4..+3,
// n = (t>>2) + 64k for k in 0..17.

#define BATCH 256
#define CAPS  10
#define NIN   1152
#define DIN   8
#define UDIM  16
#define KITER 18   // NIN / 64

__global__ __launch_bounds__(256, 3) void capsule_routing_kernel(
    const float* __restrict__ x,   // (B, N, Din)
    const float* __restrict__ W,   // (C, N, Din, U)
    float* __restrict__ out)       // (B, C, U)
{
    const int gblk = blockIdx.x;      // 0..2559, c-major for L2 temporal locality
    const int c    = gblk >> 8;       // 0..9
    const int b    = gblk & 255;      // 0..255
    const int t    = threadIdx.x;     // 0..255
    const int ub   = (t & 3) << 2;    // u base: 0,4,8,12
    const int gg   = t >> 2;          // 0..63 (n residue)
    const int wave = t >> 6;          // 0..3

    __shared__ float x_s[NIN * DIN];  // 36 KB staged input row
    __shared__ float b_s[NIN];        // routing logits
    __shared__ float e_s[NIN];        // exp(b - max)
    __shared__ float redA[4];
    __shared__ float redB[4];
    __shared__ float ps[4][UDIM];     // per-wave partial s
    __shared__ float v_s[UDIM];       // squashed output vector

    // ---- stage x[b] into LDS (coalesced float4) ----
    {
        const float4* xg = (const float4*)(x + (size_t)b * (NIN * DIN));
        float4* xs = (float4*)x_s;
        #pragma unroll
        for (int i = 0; i < (NIN * DIN / 4) / 256; ++i)
            xs[t + 256 * i] = xg[t + 256 * i];
    }
    for (int n = t; n < NIN; n += 256) b_s[n] = 1.0f;
    __syncthreads();

    // ---- compute u_hat into registers ----
    float uh[KITER][4];
    const float* Wc = W + (size_t)c * (NIN * DIN * UDIM);
    #pragma unroll
    for (int k = 0; k < KITER; ++k) {
        const int n = gg + 64 * k;
        const float4* wr = (const float4*)(Wc + n * (DIN * UDIM) + ub);
        const float4 x0 = ((const float4*)(x_s + n * DIN))[0];
        const float4 x1 = ((const float4*)(x_s + n * DIN))[1];
        const float xv[8] = {x0.x, x0.y, x0.z, x0.w, x1.x, x1.y, x1.z, x1.w};
        float a0 = 0.f, a1 = 0.f, a2 = 0.f, a3 = 0.f;
        #pragma unroll
        for (int i = 0; i < 8; ++i) {
            const float4 w = wr[4 * i];   // W[c][n][i][ub..ub+3]
            a0 += xv[i] * w.x; a1 += xv[i] * w.y;
            a2 += xv[i] * w.z; a3 += xv[i] * w.w;
        }
        uh[k][0] = a0; uh[k][1] = a1; uh[k][2] = a2; uh[k][3] = a3;
    }

    // ---- 3 routing iterations ----
    for (int it = 0; it < 3; ++it) {
        // block max of b_s (softmax stabilization)
        float m = -INFINITY;
        for (int n = t; n < NIN; n += 256) m = fmaxf(m, b_s[n]);
        #pragma unroll
        for (int mk = 1; mk <= 32; mk <<= 1) m = fmaxf(m, __shfl_xor(m, mk));
        if ((t & 63) == 0) redA[wave] = m;
        __syncthreads();
        const float bmax = fmaxf(fmaxf(redA[0], redA[1]), fmaxf(redA[2], redA[3]));

        // exp + block sum
        float le = 0.f;
        for (int n = t; n < NIN; n += 256) {
            const float e = expf(b_s[n] - bmax);
            e_s[n] = e;
            le += e;
        }
        #pragma unroll
        for (int mk = 1; mk <= 32; mk <<= 1) le += __shfl_xor(le, mk);
        if ((t & 63) == 0) redB[wave] = le;
        __syncthreads();
        const float inv = 1.0f / (redB[0] + redB[1] + redB[2] + redB[3]);

        // s[u] = (sum_n e[n] * u_hat[n][u]) * inv
        float p0 = 0.f, p1 = 0.f, p2 = 0.f, p3 = 0.f;
        #pragma unroll
        for (int k = 0; k < KITER; ++k) {
            const float e = e_s[gg + 64 * k];
            p0 += e * uh[k][0]; p1 += e * uh[k][1];
            p2 += e * uh[k][2]; p3 += e * uh[k][3];
        }
        #pragma unroll
        for (int mk = 4; mk <= 32; mk <<= 1) {
            p0 += __shfl_xor(p0, mk); p1 += __shfl_xor(p1, mk);
            p2 += __shfl_xor(p2, mk); p3 += __shfl_xor(p3, mk);
        }
        if ((t & 63) < 4) {   // lanes 0..3 hold quad sums for ub = lane*4
            ps[wave][ub + 0] = p0; ps[wave][ub + 1] = p1;
            ps[wave][ub + 2] = p2; ps[wave][ub + 3] = p3;
        }
        __syncthreads();

        // squash on first 16 threads
        if (t < UDIM) {
            const float s = (ps[0][t] + ps[1][t] + ps[2][t] + ps[3][t]) * inv;
            float sq = s * s;
            #pragma unroll
            for (int mk = 1; mk <= 8; mk <<= 1) sq += __shfl_xor(sq, mk);
            const float scale = sq / ((1.0f + sq) * sqrtf(sq + 1e-9f));
            const float v = scale * s;
            v_s[t] = v;
            if (it == 2) out[((size_t)b * CAPS + c) * UDIM + t] = v;
        }
        __syncthreads();

        // b[n] += u_hat[n] . v
        if (it < 2) {
            #pragma unroll
            for (int k = 0; k < KITER; ++k) {
                float q = uh[k][0] * v_s[ub + 0] + uh[k][1] * v_s[ub + 1]
                        + uh[k][2] * v_s[ub + 2] + uh[k][3] * v_s[ub + 3];
                q += __shfl_xor(q, 1);
                q += __shfl_xor(q, 2);
                if ((t & 3) == 0) b_s[gg + 64 * k] += q;
            }
            __syncthreads();
        }
    }
}

extern "C" void kernel_launch(void* const* d_in, const int* in_sizes, int n_in,
                              void* d_out, int out_size, void* d_ws, size_t ws_size,
                              hipStream_t stream) {
    const float* x = (const float*)d_in[0];   // (256, 1152, 8)
    const float* W = (const float*)d_in[1];   // (10, 1152, 8, 16)
    float* out = (float*)d_out;               // (256, 10, 16)
    capsule_routing_kernel<<<BATCH * CAPS, 256, 0, stream>>>(x, W, out);
}